// Round 7
// baseline (1020.952 us; speedup 1.0000x reference)
//
#include <hip/hip_runtime.h>
#include <hip/hip_fp16.h>
#include <cstdint>

#define GRAPHS 128

// ---------------- edge prep: degrees (dst+src), scans, fused scatter ----------------

__global__ __launch_bounds__(256) void k_deg2(const int* __restrict__ ei, int E, int ET,
                                              int* __restrict__ ddeg, int* __restrict__ sdeg) {
  int e = blockIdx.x * 256 + threadIdx.x;
  if (e >= ET) return;
  int s, d;
  if (e < E) { s = ei[e]; d = ei[E + e]; } else { s = d = e - E; }
  atomicAdd(&ddeg[d], 1);
  atomicAdd(&sdeg[s], 1);
}

__global__ __launch_bounds__(256) void k_s1(const int* __restrict__ deg, int N,
                                            int* __restrict__ bsum) {
  int b = blockIdx.x, tid = threadIdx.x;
  int i0 = b * 1024 + tid * 4;
  int s = 0;
#pragma unroll
  for (int e = 0; e < 4; ++e) { int i = i0 + e; if (i < N) s += deg[i]; }
#pragma unroll
  for (int o = 32; o; o >>= 1) s += __shfl_xor(s, o);
  __shared__ int wt[4];
  int lane = tid & 63, wid = tid >> 6;
  if (lane == 0) wt[wid] = s;
  __syncthreads();
  if (tid == 0) bsum[b] = wt[0] + wt[1] + wt[2] + wt[3];
}

__global__ void k_s2(int* bsum, int nb) {
  if (threadIdx.x == 0) {
    int run = 0;
    for (int i = 0; i < nb; ++i) { int t = bsum[i]; bsum[i] = run; run += t; }
  }
}

__global__ __launch_bounds__(256) void k_s3(int* __restrict__ deg_cursor,
                                            const int* __restrict__ bsum,
                                            int* __restrict__ rowptr, int N) {
  int b = blockIdx.x, tid = threadIdx.x;
  int lane = tid & 63, wid = tid >> 6;
  int i0 = b * 1024 + tid * 4;
  int d[4];
#pragma unroll
  for (int e = 0; e < 4; ++e) { int i = i0 + e; d[e] = (i < N) ? deg_cursor[i] : 0; }
  int p0 = d[0], p1 = p0 + d[1], p2 = p1 + d[2], p3 = p2 + d[3];
  int incl = p3;
#pragma unroll
  for (int o = 1; o < 64; o <<= 1) { int u = __shfl_up(incl, o); if (lane >= o) incl += u; }
  __shared__ int wt[4];
  if (lane == 63) wt[wid] = incl;
  __syncthreads();
  int woff = 0;
  for (int w = 0; w < wid; ++w) woff += wt[w];
  int ex = bsum[b] + woff + incl - p3;
  int pre[4] = {0, p0, p1, p2};
#pragma unroll
  for (int e = 0; e < 4; ++e) {
    int i = i0 + e;
    if (i < N) { int st = ex + pre[e]; deg_cursor[i] = st; rowptr[i + 1] = st + d[e]; }
  }
  if (b == 0 && tid == 0) rowptr[0] = 0;
}

// fused scatter: dst-CSR (csrs = src per dst-pos) + position maps dst<->src order
__global__ __launch_bounds__(256) void k_scatter2(const int* __restrict__ ei, int E, int ET,
                                                  int* __restrict__ dcur, int* __restrict__ scur,
                                                  int* __restrict__ csrs,
                                                  int* __restrict__ s2ds, int* __restrict__ ds2s) {
  int e = blockIdx.x * 256 + threadIdx.x;
  if (e >= ET) return;
  int s, d;
  if (e < E) { s = ei[e]; d = ei[E + e]; } else { s = d = e - E; }
  int pd = atomicAdd(&dcur[d], 1);
  int ps = atomicAdd(&scur[s], 1);
  csrs[pd] = s;
  ds2s[pd] = ps;
  s2ds[ps] = pd;
}

// ---------------- GEMM (64x64 tile, 4x4/thread), fp16 C, fused attention dots ----------------

__global__ __launch_bounds__(256) void k_gemm_att(
    const float* __restrict__ A, const float* __restrict__ B, __half* __restrict__ C,
    const float* __restrict__ attS, const float* __restrict__ attD,
    float* __restrict__ aS, float* __restrict__ aD, int M, int K, int NC, int astr) {
  __shared__ float As[64][68];
  __shared__ float Bs[64][64];
  int tid = threadIdx.x;
  int tx = tid & 15, ty = tid >> 4;
  int m0 = blockIdx.x * 64, n0 = blockIdx.y * 64;
  float acc[4][4] = {};
  for (int kc = 0; kc < K; kc += 64) {
    int r = tid >> 4;
    int f4 = tid & 15;
#pragma unroll
    for (int p = 0; p < 4; ++p) {
      int row = r + p * 16;
      int gm = m0 + row;
      float4 v = make_float4(0.f, 0.f, 0.f, 0.f);
      if (gm < M) v = *(const float4*)&A[(size_t)gm * K + kc + f4 * 4];
      As[f4 * 4 + 0][row] = v.x; As[f4 * 4 + 1][row] = v.y;
      As[f4 * 4 + 2][row] = v.z; As[f4 * 4 + 3][row] = v.w;
      float4 w = *(const float4*)&B[(size_t)(kc + row) * NC + n0 + f4 * 4];
      *(float4*)&Bs[row][f4 * 4] = w;
    }
    __syncthreads();
#pragma unroll 4
    for (int k = 0; k < 64; ++k) {
      float4 a4 = *(const float4*)&As[k][ty * 4];
      float4 b4 = *(const float4*)&Bs[k][tx * 4];
      acc[0][0] += a4.x * b4.x; acc[0][1] += a4.x * b4.y; acc[0][2] += a4.x * b4.z; acc[0][3] += a4.x * b4.w;
      acc[1][0] += a4.y * b4.x; acc[1][1] += a4.y * b4.y; acc[1][2] += a4.y * b4.z; acc[1][3] += a4.y * b4.w;
      acc[2][0] += a4.z * b4.x; acc[2][1] += a4.z * b4.y; acc[2][2] += a4.z * b4.z; acc[2][3] += a4.z * b4.w;
      acc[3][0] += a4.w * b4.x; acc[3][1] += a4.w * b4.y; acc[3][2] += a4.w * b4.z; acc[3][3] += a4.w * b4.w;
    }
    __syncthreads();
  }
  int head = blockIdx.y;
  float asv[4], adv[4];
#pragma unroll
  for (int ci = 0; ci < 4; ++ci) { asv[ci] = attS[n0 + tx * 4 + ci]; adv[ci] = attD[n0 + tx * 4 + ci]; }
#pragma unroll
  for (int ri = 0; ri < 4; ++ri) {
    int gm = m0 + ty * 4 + ri;
    if (gm < M) {
      __half2 p01 = __halves2half2(__float2half(acc[ri][0]), __float2half(acc[ri][1]));
      __half2 p23 = __halves2half2(__float2half(acc[ri][2]), __float2half(acc[ri][3]));
      size_t cidx = (size_t)gm * NC + n0 + tx * 4;
      *(__half2*)&C[cidx] = p01;
      *(__half2*)&C[cidx + 2] = p23;
    }
    float s = acc[ri][0] * asv[0] + acc[ri][1] * asv[1] + acc[ri][2] * asv[2] + acc[ri][3] * asv[3];
    float d = acc[ri][0] * adv[0] + acc[ri][1] * adv[1] + acc[ri][2] * adv[2] + acc[ri][3] * adv[3];
#pragma unroll
    for (int o2 = 1; o2 < 16; o2 <<= 1) { s += __shfl_xor(s, o2); d += __shfl_xor(d, o2); }
    if (tx == 0 && gm < M) { aS[(size_t)gm * astr + head] = s; aD[(size_t)gm * astr + head] = d; }
  }
}

// ---------------- per-edge softmax coefs (wave-per-dst), scattered into SRC order ----------------

template <int NH>
__global__ __launch_bounds__(256) void k_coef(
    const int* __restrict__ rowptr, const int* __restrict__ csrs, const int* __restrict__ ds2s,
    const float* __restrict__ aS, const float* __restrict__ aD,
    float* __restrict__ coefS, int N, int ETp) {
  constexpr int ASTR = (NH == 3) ? 4 : 1;
  int wv = (blockIdx.x * 256 + (int)threadIdx.x) >> 6;
  if (wv >= N) return;
  int lane = threadIdx.x & 63;
  int start = rowptr[wv], end = rowptr[wv + 1];
  float ad[NH], m[NH], s[NH];
#pragma unroll
  for (int h = 0; h < NH; ++h) { ad[h] = aD[(size_t)wv * ASTR + h]; m[h] = -1e30f; s[h] = 0.f; }
  for (int j = start + lane; j < end; j += 64) {
    int sb = csrs[j];
    float av[NH];
    if (NH == 3) {
      float4 a4 = *(const float4*)&aS[(size_t)sb * 4];
      av[0] = a4.x; av[1] = a4.y; av[2] = a4.z;
    } else {
      av[0] = aS[sb];
    }
#pragma unroll
    for (int h = 0; h < NH; ++h) {
      float v = av[h] + ad[h];
      v = v > 0.f ? v : 0.2f * v;
      float M = fmaxf(m[h], v);
      s[h] = s[h] * __expf(m[h] - M) + __expf(v - M);
      m[h] = M;
    }
  }
#pragma unroll
  for (int h = 0; h < NH; ++h) {
    float mm = m[h], ss = s[h];
#pragma unroll
    for (int o = 1; o < 64; o <<= 1) {
      float om = __shfl_xor(mm, o), os = __shfl_xor(ss, o);
      float M = fmaxf(mm, om);
      ss = ss * __expf(mm - M) + os * __expf(om - M);
      mm = M;
    }
    m[h] = mm;
    s[h] = 1.0f / fmaxf(ss, 1e-16f);
  }
  for (int j = start + lane; j < end; j += 64) {
    int sb = csrs[j];
    int ks = ds2s[j];  // src-CSR position
    float av[NH];
    if (NH == 3) {
      float4 a4 = *(const float4*)&aS[(size_t)sb * 4];
      av[0] = a4.x; av[1] = a4.y; av[2] = a4.z;
    } else {
      av[0] = aS[sb];
    }
#pragma unroll
    for (int h = 0; h < NH; ++h) {
      float v = av[h] + ad[h];
      v = v > 0.f ? v : 0.2f * v;
      coefS[(size_t)h * ETp + ks] = __expf(v - m[h]) * s[h];
    }
  }
}

// ---------------- phase A: src-major push. Read own row once, scattered 64B Ev row stores ----
// wave = 4 src nodes (16 lanes each, 2 cols/lane -> 32-col slice).

template <int XPH>
__global__ __launch_bounds__(256) void k_pushA(
    const int* __restrict__ srcptr, const int* __restrict__ s2ds,
    const float* __restrict__ coefS, const __half* __restrict__ xp, int coloff,
    __half* __restrict__ Ev, int N) {
  int tid = threadIdx.x;
  int wv = (blockIdx.x * 256 + tid) >> 6;
  int lane = tid & 63;
  int q = lane >> 4, l16 = lane & 15;
  int s = wv * 4 + q;
  bool sv = s < N;
  int kb = 0, ke = 0;
  float2 f = make_float2(0.f, 0.f);
  if (sv) {
    kb = srcptr[s]; ke = srcptr[s + 1];
    __half2 hv = *(const __half2*)&xp[(size_t)s * XPH + coloff + l16 * 2];
    f = __half22float2(hv);
  }
  for (int it = 0; ; ++it) {
    int k = kb + it;
    bool a = sv && (k < ke);
    if (!__any(a)) break;
    if (a) {
      int pd = s2ds[k];     // dst-CSR position (Ev row)
      float c = coefS[k];   // coalesced per slot
      __half2 hv = __halves2half2(__float2half(c * f.x), __float2half(c * f.y));
      *(__half2*)&Ev[(size_t)pd * 32 + l16 * 2] = hv;
    }
  }
}

// ---------------- phase B: dst-major sequential segmented sum over Ev ----------------

template <bool DOELU, bool POOL>
__global__ __launch_bounds__(256) void k_pushB(
    const int* __restrict__ rowptr, const __half* __restrict__ Ev,
    const float* __restrict__ bias, int coloff, int OUTS, float* __restrict__ out,
    const int* __restrict__ batch, float* __restrict__ pooled, float* __restrict__ gcnt,
    int docnt, int N) {
  int tid = threadIdx.x;
  int wv = (blockIdx.x * 256 + tid) >> 6;
  int lane = tid & 63;
  int q = lane >> 4, l16 = lane & 15;
  int n = wv * 4 + q;
  bool nv = n < N;
  int jb = 0, je = 0;
  if (nv) { jb = rowptr[n]; je = rowptr[n + 1]; }
  float a0 = 0.f, a1 = 0.f;
  for (int j = jb; j < je; ++j) {
    __half2 hv = *(const __half2*)&Ev[(size_t)j * 32 + l16 * 2];
    float2 fv = __half22float2(hv);
    a0 += fv.x; a1 += fv.y;
  }
  if (!nv) return;
  int col = coloff + l16 * 2;
  float v0 = a0 + bias[col], v1 = a1 + bias[col + 1];
  if (DOELU) {
    v0 = v0 > 0.f ? v0 : __expf(v0) - 1.f;
    v1 = v1 > 0.f ? v1 : __expf(v1) - 1.f;
  }
  if (POOL) {
    int g = batch[n];
    atomicAdd(&pooled[g * 64 + col], v0);
    atomicAdd(&pooled[g * 64 + col + 1], v1);
    if (docnt && l16 == 0) atomicAdd(&gcnt[g], 1.f);
  } else {
    *(float2*)&out[(size_t)n * OUTS + col] = make_float2(v0, v1);
  }
}

// ---------------- final: mean + linear ----------------

__global__ __launch_bounds__(64) void k_final(const float* __restrict__ pooled,
                                              const float* __restrict__ gcnt,
                                              const float* __restrict__ lw,
                                              const float* __restrict__ lb,
                                              float* __restrict__ out) {
  int g = blockIdx.x, c = threadIdx.x;
  float inv = 1.0f / fmaxf(gcnt[g], 1.0f);
  float pv = pooled[g * 64 + c] * inv;
#pragma unroll
  for (int k = 0; k < 10; ++k) {
    float v = pv * lw[c * 10 + k];
#pragma unroll
    for (int o = 1; o < 64; o <<= 1) v += __shfl_xor(v, o);
    if (c == 0) out[g * 10 + k] = v + lb[k];
  }
}

extern "C" void kernel_launch(void* const* d_in, const int* in_sizes, int n_in,
                              void* d_out, int out_size, void* d_ws, size_t ws_size,
                              hipStream_t stream) {
  const float* x = (const float*)d_in[0];
  const int* ei = (const int*)d_in[1];
  const int* batch = (const int*)d_in[2];
  const float* W1 = (const float*)d_in[3];
  const float* as1 = (const float*)d_in[4];
  const float* ad1 = (const float*)d_in[5];
  const float* b1 = (const float*)d_in[6];
  const float* W2 = (const float*)d_in[7];
  const float* as2 = (const float*)d_in[8];
  const float* ad2 = (const float*)d_in[9];
  const float* b2 = (const float*)d_in[10];
  const float* lw = (const float*)d_in[11];
  const float* lb = (const float*)d_in[12];
  float* out = (float*)d_out;

  const int N = in_sizes[2];        // 50000
  const int E = in_sizes[1] / 2;    // 800000
  const int ET = E + N;             // + self loops
  const int F = in_sizes[0] / N;    // 128
  const int HC = in_sizes[6];       // 192
  const int LH = in_sizes[10];      // 64
  const int ETp = (ET + 255) & ~255;

  size_t off = 0;
  auto alo = [&](size_t bytes) -> char* {
    char* p = (char*)d_ws + off;
    off += (bytes + 255) & ~(size_t)255;
    return p;
  };
  int* dcur = (int*)alo((size_t)N * 4);     // ddeg then dst cursor
  int* scur = (int*)alo((size_t)N * 4);     // sdeg then src cursor
  float* pooled = (float*)alo((size_t)GRAPHS * 64 * 4);
  float* gcnt = (float*)alo((size_t)GRAPHS * 4);
  size_t zbytes = off;                      // zero everything above
  int* rowptrD = (int*)alo(((size_t)N + 1) * 4);
  int* rowptrS = (int*)alo(((size_t)N + 1) * 4);
  int* csrs = (int*)alo((size_t)ET * 4);
  int* s2ds = (int*)alo((size_t)ET * 4);
  int* ds2s = (int*)alo((size_t)ET * 4);
  float* aS1 = (float*)alo((size_t)N * 4 * 4);
  float* aD1 = (float*)alo((size_t)N * 4 * 4);
  float* aS2 = (float*)alo((size_t)N * 4);
  float* aD2 = (float*)alo((size_t)N * 4);
  int* bsumD = (int*)alo(64 * 4);
  int* bsumS = (int*)alo(64 * 4);
  float* coefS = (float*)alo((size_t)3 * ETp * 4);   // planar [head][src-pos]
  __half* xp1 = (__half*)alo((size_t)N * 192 * 2);
  float* h1 = (float*)alo((size_t)N * 192 * 4);
  __half* xp2 = (__half*)alo((size_t)N * 64 * 2);
  __half* Ev = (__half*)alo((size_t)ETp * 32 * 2);   // one 32-col fp16 slice

  hipMemsetAsync(d_ws, 0, zbytes, stream);
  int eb = (ET + 255) / 256;
  k_deg2<<<eb, 256, 0, stream>>>(ei, E, ET, dcur, scur);
  int nb = (N + 1023) / 1024;
  k_s1<<<nb, 256, 0, stream>>>(dcur, N, bsumD);
  k_s2<<<1, 64, 0, stream>>>(bsumD, nb);
  k_s3<<<nb, 256, 0, stream>>>(dcur, bsumD, rowptrD, N);
  k_s1<<<nb, 256, 0, stream>>>(scur, N, bsumS);
  k_s2<<<1, 64, 0, stream>>>(bsumS, nb);
  k_s3<<<nb, 256, 0, stream>>>(scur, bsumS, rowptrS, N);
  k_scatter2<<<eb, 256, 0, stream>>>(ei, E, ET, dcur, scur, csrs, s2ds, ds2s);

  int ab = (N + 3) / 4;     // wave-per-node kernels
  int pb = (N + 15) / 16;   // 4-nodes-per-wave pass kernels

  // ---- layer 1 ----
  dim3 g1((N + 63) / 64, HC / 64);
  k_gemm_att<<<g1, 256, 0, stream>>>(x, W1, xp1, as1, ad1, aS1, aD1, N, F, HC, 4);
  k_coef<3><<<ab, 256, 0, stream>>>(rowptrD, csrs, ds2s, aS1, aD1, coefS, N, ETp);
  for (int p = 0; p < 6; ++p) {
    k_pushA<192><<<pb, 256, 0, stream>>>(rowptrS, s2ds, coefS + (size_t)(p >> 1) * ETp,
                                         xp1, p * 32, Ev, N);
    k_pushB<true, false><<<pb, 256, 0, stream>>>(rowptrD, Ev, b1, p * 32, 192, h1,
                                                 nullptr, nullptr, nullptr, 0, N);
  }
  // ---- layer 2 ----
  dim3 g2((N + 63) / 64, LH / 64);
  k_gemm_att<<<g2, 256, 0, stream>>>(h1, W2, xp2, as2, ad2, aS2, aD2, N, HC, LH, 1);
  k_coef<1><<<ab, 256, 0, stream>>>(rowptrD, csrs, ds2s, aS2, aD2, coefS, N, ETp);
  for (int p = 0; p < 2; ++p) {
    k_pushA<64><<<pb, 256, 0, stream>>>(rowptrS, s2ds, coefS, xp2, p * 32, Ev, N);
    k_pushB<false, true><<<pb, 256, 0, stream>>>(rowptrD, Ev, b2, p * 32, 0, nullptr,
                                                 batch, pooled, gcnt, p == 0 ? 1 : 0, N);
  }
  k_final<<<GRAPHS, 64, 0, stream>>>(pooled, gcnt, lw, lb, out);
}